// Round 1
// baseline (197.569 us; speedup 1.0000x reference)
//
#include <hip/hip_runtime.h>
#include <cstdint>

#define N 8192
#define BLK 256
#define NBLOCKS 4096   // block b handles rows b and (N-2-b); combined length == N

// Per-thread partial of sum_{e in [0,L)} c2[O+e] * x[i+1+e], strided over the block.
// float4-vectorized with alignment prolog/tail (row offsets are arbitrary mod 4).
__device__ __forceinline__ float row_partial(const float* __restrict__ c2,
                                             const float* __restrict__ x,
                                             long long O, int L, int i) {
    const int t = threadIdx.x;
    const float* cp = c2 + O;
    const float* xp = x + i + 1;
    float s = 0.0f;

    int pro = (int)((4 - (O & 3)) & 3);   // scalar elems until 16B alignment
    if (pro > L) pro = L;
    if (t < pro) s += cp[t] * xp[t];

    const int R = L - pro;
    const int V = R >> 2;      // # of float4's
    const int tail = R & 3;

    const float4* __restrict__ cv = (const float4*)(cp + pro);
    const float*  __restrict__ xv = xp + pro;
    for (int v = t; v < V; v += BLK) {
        float4 c = cv[v];
        const int e = v << 2;
        s += c.x * xv[e] + c.y * xv[e + 1] + c.z * xv[e + 2] + c.w * xv[e + 3];
    }
    if (t < tail) {
        const int e = (V << 2) + t;
        s += cp[pro + e] * xv[e];
    }
    return s;
}

__global__ __launch_bounds__(BLK) void ham_main(const float* __restrict__ x,
                                                const float* __restrict__ coeffs,
                                                float* __restrict__ ws) {
    const int b = blockIdx.x;
    const int t = threadIdx.x;
    const float* __restrict__ c1 = coeffs;
    const float* __restrict__ c2 = coeffs + N;

    float acc = 0.0f;

    // Row i1 = b  (length N-1-b)
    {
        const int i1 = b;
        const long long O1 = (long long)i1 * (2LL * N - i1 - 1) / 2;
        const int L1 = N - 1 - i1;
        const float s1 = row_partial(c2, x, O1, L1, i1);
        acc += x[i1] * s1;
    }
    // Row i2 = N-2-b  (length b+1); middle row (b==4095) appears only once
    {
        const int i2 = N - 2 - b;
        if (i2 > b) {
            const long long O2 = (long long)i2 * (2LL * N - i2 - 1) / 2;
            const int L2 = N - 1 - i2;
            const float s2 = row_partial(c2, x, O2, L2, i2);
            acc += x[i2] * s2;
        }
    }

    // Degree-1 terms: first 32 blocks cover 8192 elements
    {
        const int g = b * BLK + t;
        if (g < N) acc += c1[g] * x[g];
    }

    // Block reduction: wave shuffle (64-wide) then LDS across 4 waves
    #pragma unroll
    for (int o = 32; o > 0; o >>= 1) acc += __shfl_down(acc, o, 64);
    __shared__ float smem[BLK / 64];
    const int wave = t >> 6;
    const int lane = t & 63;
    if (lane == 0) smem[wave] = acc;
    __syncthreads();
    if (t == 0) {
        float v = 0.0f;
        #pragma unroll
        for (int w = 0; w < BLK / 64; ++w) v += smem[w];
        ws[b] = v;   // unconditional write: d_ws is poisoned, never read-before-write
    }
}

__global__ __launch_bounds__(1024) void ham_reduce(const float* __restrict__ ws,
                                                   float* __restrict__ out) {
    const int t = threadIdx.x;
    float v = 0.0f;
    for (int idx = t; idx < NBLOCKS; idx += 1024) v += ws[idx];
    #pragma unroll
    for (int o = 32; o > 0; o >>= 1) v += __shfl_down(v, o, 64);
    __shared__ float smem[16];
    const int wave = t >> 6;
    const int lane = t & 63;
    if (lane == 0) smem[wave] = v;
    __syncthreads();
    if (t == 0) {
        float s = 0.0f;
        #pragma unroll
        for (int w = 0; w < 16; ++w) s += smem[w];
        out[0] = s;
    }
}

extern "C" void kernel_launch(void* const* d_in, const int* in_sizes, int n_in,
                              void* d_out, int out_size, void* d_ws, size_t ws_size,
                              hipStream_t stream) {
    const float* x      = (const float*)d_in[0];
    const float* coeffs = (const float*)d_in[1];
    float* out = (float*)d_out;
    float* ws  = (float*)d_ws;   // needs NBLOCKS*4 = 16 KB

    ham_main<<<NBLOCKS, BLK, 0, stream>>>(x, coeffs, ws);
    ham_reduce<<<1, 1024, 0, stream>>>(ws, out);
}